// Round 2
// baseline (813.102 us; speedup 1.0000x reference)
//
#include <hip/hip_runtime.h>
#include <math.h>

// MoE router: N=16384 tokens, D=4096, E=64 experts, top-8.
// K1: logits = (x*(0.99+0.02*noise)) @ W  -- f32, wave-private split-K:
//     8 waves/block, 64 rows (row=lane), wave w owns k in [512w,512w+512),
//     acc[64] experts per lane, W via wave-uniform (SGPR) loads, x via
//     per-wave LDS chunks, register double-buffer prefetch, NO barriers
//     in the k-loop. Deterministic 8-phase LDS reduction at the end.
// K2: softmax -> biased top-8 (tie: lower index) -> L2-norm weights -> hist.

#define N_TOK 16384
#define DIM   4096
#define NEXP  64
#define TOPK  8

#define CHUNK 16
#define SLICE 512
#define NCH   (SLICE / CHUNK)      // 32 chunks per wave slice
#define XS_STR 5                   // float4 stride per row (16 k + 4 pad)
#define WBUF_F4 (64 * XS_STR)      // 320 float4 per wave buffer

__global__ __launch_bounds__(512, 2) void gemm_logits_kernel(
    const float* __restrict__ x, const float* __restrict__ Wm,
    const float* __restrict__ noise, float* __restrict__ logits)
{
    __shared__ float4 pool[8 * WBUF_F4];   // 40960 B; reused for reduction
    const int t    = threadIdx.x;
    const int lane = t & 63;
    const int w    = __builtin_amdgcn_readfirstlane(t >> 6);  // wave id, uniform
    const int rowBase = blockIdx.x * 64;

    float4* wbuf = pool + w * WBUF_F4;
    const float4* W4 = (const float4*)Wm;

    float acc[NEXP];
#pragma unroll
    for (int e = 0; e < NEXP; ++e) acc[e] = 0.0f;

    const int srow = lane >> 2;   // staging row within 16-row group
    const int sc4  = lane & 3;    // staging f4-column within chunk

    float4 pxA[4], pnA[4], pxB[4], pnB[4];

    // issue global loads for chunk c into (px,pn)
    auto issue = [&](int c, float4* px, float4* pn) {
        const int k0 = w * SLICE + c * CHUNK;
#pragma unroll
        for (int i = 0; i < 4; ++i) {
            const size_t g = (size_t)(rowBase + i * 16 + srow) * DIM
                           + (size_t)(k0 + sc4 * 4);
            px[i] = *(const float4*)(x + g);
            pn[i] = *(const float4*)(noise + g);
        }
    };

    // jitter + write chunk to this wave's LDS buffer
    auto stage = [&](const float4* px, const float4* pn) {
#pragma unroll
        for (int i = 0; i < 4; ++i) {
            float4 j;
            j.x = px[i].x * (0.99f + 0.02f * pn[i].x);
            j.y = px[i].y * (0.99f + 0.02f * pn[i].y);
            j.z = px[i].z * (0.99f + 0.02f * pn[i].z);
            j.w = px[i].w * (0.99f + 0.02f * pn[i].w);
            wbuf[(i * 16 + srow) * XS_STR + sc4] = j;
        }
    };

    // consume chunk c from LDS: 16 k x 64 experts of FMA, W wave-uniform
    auto compute = [&](int c) {
        const int kbase = w * SLICE + c * CHUNK;
#pragma unroll
        for (int kk4 = 0; kk4 < 4; ++kk4) {
            const float4 xv = wbuf[lane * XS_STR + kk4];
            const float xa[4] = { xv.x, xv.y, xv.z, xv.w };
#pragma unroll
            for (int j = 0; j < 4; ++j) {
                const int k = kbase + kk4 * 4 + j;
                const float xs = xa[j];
#pragma unroll
                for (int e4 = 0; e4 < 16; ++e4) {
                    const float4 wv = W4[(size_t)k * 16 + e4];  // uniform -> s_load
                    acc[e4 * 4 + 0] += xs * wv.x;
                    acc[e4 * 4 + 1] += xs * wv.y;
                    acc[e4 * 4 + 2] += xs * wv.z;
                    acc[e4 * 4 + 3] += xs * wv.w;
                }
            }
        }
    };

    issue(0, pxA, pnA);
    issue(1, pxB, pnB);
    for (int c = 0; c < NCH; c += 2) {
        stage(pxA, pnA);
        issue(min(c + 2, NCH - 1), pxA, pnA);
        compute(c);
        stage(pxB, pnB);
        issue(min(c + 3, NCH - 1), pxB, pnB);
        compute(c + 1);
    }

    // ---- deterministic cross-wave reduction: red[64 rows][68 floats] ----
    __syncthreads();
    float4* red4 = pool;           // 64*17 f4 = 17408 B <= pool
    const int RSTR = 17;
    for (int ph = 0; ph < 8; ++ph) {
        if (w == ph) {
#pragma unroll
            for (int e4 = 0; e4 < 16; ++e4) {
                float4 v;
                v.x = acc[e4 * 4 + 0]; v.y = acc[e4 * 4 + 1];
                v.z = acc[e4 * 4 + 2]; v.w = acc[e4 * 4 + 3];
                if (ph == 0) {
                    red4[lane * RSTR + e4] = v;
                } else {
                    float4 o = red4[lane * RSTR + e4];
                    o.x += v.x; o.y += v.y; o.z += v.z; o.w += v.w;
                    red4[lane * RSTR + e4] = o;
                }
            }
        }
        __syncthreads();
    }

    // store: wave w writes rows 8w..8w+7, coalesced f4
    const int e4s = lane & 15, rl = lane >> 4;
#pragma unroll
    for (int rr = 0; rr < 2; ++rr) {
        const int row = w * 8 + rr * 4 + rl;
        const float4 v = red4[row * RSTR + e4s];
        *(float4*)(logits + (size_t)(rowBase + row) * NEXP + e4s * 4) = v;
    }
}

__global__ __launch_bounds__(256) void router_topk_kernel(
    const float* __restrict__ logits, const float* __restrict__ score_bias,
    float* __restrict__ scores, float* __restrict__ weights,
    float* __restrict__ indicesF, float* __restrict__ histF)
{
    __shared__ int hist[NEXP];
    const int t = threadIdx.x;
    if (t < NEXP) hist[t] = 0;
    __syncthreads();

    const int lane = t & 63;
    const int w    = t >> 6;            // wave id 0..3
    const float bias = score_bias[lane];
    const int base = blockIdx.x * 16;   // 16 rows per block, 1024 blocks

    for (int it = 0; it < 4; ++it) {
        const int row = base + w * 4 + it;
        const float lg = logits[(size_t)row * NEXP + lane];

        // softmax (wave butterfly over 64 lanes)
        float mx = lg;
#pragma unroll
        for (int off = 32; off > 0; off >>= 1)
            mx = fmaxf(mx, __shfl_xor(mx, off));
        const float p = expf(lg - mx);
        float s = p;
#pragma unroll
        for (int off = 32; off > 0; off >>= 1)
            s += __shfl_xor(s, off);
        const float sc = p / s;
        scores[(size_t)row * NEXP + lane] = sc;

        // biased top-8, tie -> lower index (jax.lax.top_k semantics)
        float v = sc + bias;
        int myIdx = 0; float myW = 0.0f;
        float ssq = 0.0f;
#pragma unroll
        for (int k = 0; k < TOPK; ++k) {
            float bv = v; int bi = lane;
#pragma unroll
            for (int off = 32; off > 0; off >>= 1) {
                const float ov = __shfl_xor(bv, off);
                const int   oi = __shfl_xor(bi, off);
                if (ov > bv || (ov == bv && oi < bi)) { bv = ov; bi = oi; }
            }
            const float wk = __shfl(sc, bi);
            ssq += wk * wk;
            if (lane == k)  { myIdx = bi; myW = wk; }
            if (lane == bi) v = -INFINITY;
        }

        if (lane < TOPK) {
            const float norm = sqrtf(ssq);
            weights[(size_t)row * TOPK + lane]  = myW / norm;
            indicesF[(size_t)row * TOPK + lane] = (float)myIdx;
            atomicAdd(&hist[myIdx], 1);
        }
    }

    __syncthreads();
    if (t < NEXP && hist[t] != 0) atomicAdd(&histF[t], (float)hist[t]);
}

extern "C" void kernel_launch(void* const* d_in, const int* in_sizes, int n_in,
                              void* d_out, int out_size, void* d_ws, size_t ws_size,
                              hipStream_t stream)
{
    const float* x     = (const float*)d_in[0];
    const float* W     = (const float*)d_in[1];
    const float* sbias = (const float*)d_in[2];
    const float* noise = (const float*)d_in[3];

    float* out      = (float*)d_out;
    float* logits   = out;                                    // 16384*64
    float* scores   = out + (size_t)N_TOK * NEXP;             // 16384*64
    float* weights  = out + 2ull * N_TOK * NEXP;              // 16384*8
    float* indicesF = weights + (size_t)N_TOK * TOPK;         // 16384*8
    float* histF    = indicesF + (size_t)N_TOK * TOPK;        // 64

    gemm_logits_kernel<<<N_TOK / 64, 512, 0, stream>>>(x, W, noise, logits);
    hipMemsetAsync(histF, 0, NEXP * sizeof(float), stream);
    router_topk_kernel<<<N_TOK / 16, 256, 0, stream>>>(logits, sbias, scores,
                                                       weights, indicesF, histF);
}